// Round 5
// baseline (1050.763 us; speedup 1.0000x reference)
//
#include <hip/hip_runtime.h>
#include <stdint.h>
#include <stddef.h>

// Problem constants
#define Bz  4
#define Tz  2048
#define Dz  2048
#define Hz  16
#define DHz 128
#define Mz  (Bz * Tz)   // 8192 rows

typedef __attribute__((ext_vector_type(4))) float  f32x4;
typedef __attribute__((ext_vector_type(8))) __bf16 bf16x8;   // 4 VGPRs = MFMA A/B frag
typedef __attribute__((ext_vector_type(8))) unsigned short u16x8;
typedef __attribute__((ext_vector_type(4))) unsigned short u16x4;

__device__ __forceinline__ unsigned short f2bf(float f) {
  union { float f; unsigned int u; } a; a.f = f;
  unsigned int u = a.u;
  u += 0x7FFFu + ((u >> 16) & 1u);            // round-to-nearest-even
  return (unsigned short)(u >> 16);
}
__device__ __forceinline__ float bf2f(unsigned short s) {
  union { unsigned int u; float f; } a; a.u = ((unsigned int)s) << 16;
  return a.f;
}
// async global->LDS, 16B per lane. LDS dest must be wave-uniform + lane*16.
__device__ __forceinline__ void load_lds16(const void* g, void* l) {
  __builtin_amdgcn_global_load_lds(
      (const __attribute__((address_space(1))) unsigned int*)g,
      (__attribute__((address_space(3))) unsigned int*)l, 16, 0, 0);
}

// ---------------- fp32 -> bf16 convert (4 elems/thread, vectorized) ----------
__global__ __launch_bounds__(256) void cvt_bf16(const float* __restrict__ in,
                         unsigned short* __restrict__ out, int n4) {
  int i = blockIdx.x * 256 + threadIdx.x;
  if (i >= n4) return;
  float4 v = reinterpret_cast<const float4*>(in)[i];
  ushort4 o;
  o.x = f2bf(v.x); o.y = f2bf(v.y); o.z = f2bf(v.z); o.w = f2bf(v.w);
  reinterpret_cast<ushort4*>(out)[i] = o;
}

// ---------------- RoPE tables: cos/sin[t][j], j in [0,64) --------------------
__global__ __launch_bounds__(256) void rope_tab(float* __restrict__ cosv,
                                                float* __restrict__ sinv) {
  int i = blockIdx.x * 256 + threadIdx.x;      // 0 .. 131071
  int t = i >> 6, j = i & 63;
  // theta_j = 10000^(-j/64) = exp(-j * ln(10000)/64)
  float theta = __expf(-(float)j * (9.210340371976184f / 64.0f));
  float ang = (float)t * theta;
  cosv[i] = cosf(ang);
  sinv[i] = sinf(ang);
}

// ---------------- RoPE apply (in-place on (B,H,T,Dh) bf16), fused q-scale ----
// out_lo = x_lo*cos - x_hi*sin ; out_hi = x_hi*cos + x_lo*sin  (rotate_half)
__global__ __launch_bounds__(256) void rope_apply(unsigned short* __restrict__ x,
                           const float* __restrict__ cosv,
                           const float* __restrict__ sinv, float scale) {
  int gid = blockIdx.x * 256 + threadIdx.x;    // B*H*T*8 = 1,048,576
  int row = gid >> 3, c = gid & 7;
  int t = row & (Tz - 1);
  int d0 = c * 8;
  unsigned short* pl = x + (size_t)row * DHz + d0;
  unsigned short* ph = pl + 64;
  u16x8 lo8 = *reinterpret_cast<const u16x8*>(pl);
  u16x8 hi8 = *reinterpret_cast<const u16x8*>(ph);
  const float* ct = cosv + t * 64 + d0;
  const float* st = sinv + t * 64 + d0;
  float4 ca = *reinterpret_cast<const float4*>(ct);
  float4 cb = *reinterpret_cast<const float4*>(ct + 4);
  float4 sa = *reinterpret_cast<const float4*>(st);
  float4 sb = *reinterpret_cast<const float4*>(st + 4);
  float cc[8] = {ca.x, ca.y, ca.z, ca.w, cb.x, cb.y, cb.z, cb.w};
  float ss[8] = {sa.x, sa.y, sa.z, sa.w, sb.x, sb.y, sb.z, sb.w};
  u16x8 nl, nh;
#pragma unroll
  for (int j = 0; j < 8; ++j) {
    float xl = bf2f(lo8[j]), xh = bf2f(hi8[j]);
    nl[j] = f2bf((xl * cc[j] - xh * ss[j]) * scale);
    nh[j] = f2bf((xh * cc[j] + xl * ss[j]) * scale);
  }
  *reinterpret_cast<u16x8*>(pl) = nl;
  *reinterpret_cast<u16x8*>(ph) = nh;
}

// ---------------- NT GEMM: out = A(M,K) * Bw(N,K)^T, bf16 in / fp32 acc ------
// m97 structure: 128x128 tile, 4 waves (2x2), BK=64, global_load_lds width 16.
// 1D grid of 1024 blocks with XCD-aware swizzle (T1; 1024%8==0 -> bijective).
// MODE 0: fp32 out, row-major (M,N)
// MODE 1: bf16 out scattered to (B,H,T,Dh)
// MODE 2: bf16 out scattered to (B,H,Dh,T)  (transposed V for attention)
template <int MODE>
__global__ __launch_bounds__(256)
void gemm_bt(const unsigned short* __restrict__ A,
             const unsigned short* __restrict__ Bw,
             void* __restrict__ outp) {
  __shared__ unsigned short Al[128 * 64];
  __shared__ unsigned short Bl[128 * 64];
  const int tid  = threadIdx.x;
  const int lane = tid & 63, wid = tid >> 6;
  const int wr = wid >> 1, wc = wid & 1;
  const int lo = lane & 15, hi = lane >> 4;
  const int w  = (blockIdx.x & 7) * 128 + (blockIdx.x >> 3);  // XCD swizzle
  const int n0 = (w & 15) * 128;
  const int m0 = (w >> 4) * 128;
  f32x4 acc[4][4] = {};

  for (int k0 = 0; k0 < Dz; k0 += 64) {
#pragma unroll
    for (int i = 0; i < 4; ++i) {
      int idx = i * 256 + tid;          // 1024 chunks of 8 bf16 (16B)
      int row = idx >> 3, ch = idx & 7;
      load_lds16(A  + (size_t)(m0 + row) * Dz + k0 + ch * 8, &Al[idx * 8]);
      load_lds16(Bw + (size_t)(n0 + row) * Dz + k0 + ch * 8, &Bl[idx * 8]);
    }
    __syncthreads();
#pragma unroll
    for (int kk = 0; kk < 2; ++kk) {
      bf16x8 a[4], b[4];
#pragma unroll
      for (int mi = 0; mi < 4; ++mi)
        a[mi] = *reinterpret_cast<const bf16x8*>(
            &Al[(wr * 64 + mi * 16 + lo) * 64 + kk * 32 + hi * 8]);
#pragma unroll
      for (int ni = 0; ni < 4; ++ni)
        b[ni] = *reinterpret_cast<const bf16x8*>(
            &Bl[(wc * 64 + ni * 16 + lo) * 64 + kk * 32 + hi * 8]);
#pragma unroll
      for (int mi = 0; mi < 4; ++mi)
#pragma unroll
        for (int ni = 0; ni < 4; ++ni)
          acc[mi][ni] = __builtin_amdgcn_mfma_f32_16x16x32_bf16(
              a[mi], b[ni], acc[mi][ni], 0, 0, 0);
    }
    __syncthreads();
  }

#pragma unroll
  for (int mi = 0; mi < 4; ++mi)
#pragma unroll
    for (int ni = 0; ni < 4; ++ni)
#pragma unroll
      for (int r = 0; r < 4; ++r) {
        // verified C/D layout: col = lane&15 (B-row), row = (lane>>4)*4 + r
        int m = m0 + wr * 64 + mi * 16 + hi * 4 + r;
        int n = n0 + wc * 64 + ni * 16 + lo;
        float v = acc[mi][ni][r];
        if (MODE == 0) {
          reinterpret_cast<float*>(outp)[(size_t)m * Dz + n] = v;
        } else if (MODE == 1) {
          int b = m >> 11, t = m & (Tz - 1);
          int h = n >> 7,  d = n & (DHz - 1);
          reinterpret_cast<unsigned short*>(outp)
              [((size_t)(b * Hz + h) * Tz + t) * DHz + d] = f2bf(v);
        } else {
          int b = m >> 11, t = m & (Tz - 1);
          int h = n >> 7,  d = n & (DHz - 1);
          reinterpret_cast<unsigned short*>(outp)
              [((size_t)(b * Hz + h) * DHz + d) * Tz + t] = f2bf(v);
        }
      }
}

// ---------------- Flash attention, bf16 MFMA 16x16x32 ------------------------
// 1D grid of 1024 blocks, XCD-swizzled: each XCD runs 8 whole heads in
// sequence -> that head's K/V (~1MB) stays hot in its private 4MB L2.
// 4 waves/block, each wave owns 32 q rows. Q pre-scaled by log2(e)/sqrt(Dh)
// (base-2 softmax). K: (B,H,T,Dh). V^T: (B,H,Dh,T). K/V read from global
// (cache-resident; guide common-mistake #7: don't stage what caches fit).
// SWAPPED QK^T (T12 idea): s = mfma(K_frag, Q_frag) => q-row lands in the
// C-layout's col (lane&15); each lane holds 16 kv-slots of ONE q-row ->
// row max/sum = 15 local ops + 2 shfl_xor (16,32), not 8 shfls per row.
__global__ __launch_bounds__(256)
void attn_fwd(const unsigned short* __restrict__ qb,
              const unsigned short* __restrict__ kb,
              const unsigned short* __restrict__ vt,
              unsigned short* __restrict__ ob) {
  __shared__ unsigned short Pl[4][32 * 64];   // per-wave P tile, XOR-swizzled
  const int tid  = threadIdx.x;
  const int lane = tid & 63, wid = tid >> 6;
  const int lo = lane & 15, hi = lane >> 4;
  const int w  = (blockIdx.x & 7) * 128 + (blockIdx.x >> 3);  // XCD swizzle
  const int bh = w >> 4;
  const int q0 = (w & 15) * 128 + wid * 32;
  const size_t base = (size_t)bh * Tz * DHz;
  const unsigned short* Q  = qb + base;
  const unsigned short* Kp = kb + base;
  const unsigned short* Vp = vt + base;       // [Dh][T] per head

  bf16x8 qf[2][4];                            // B-operand frags (rows = q)
#pragma unroll
  for (int mi = 0; mi < 2; ++mi)
#pragma unroll
    for (int kk = 0; kk < 4; ++kk)
      qf[mi][kk] = *reinterpret_cast<const bf16x8*>(
          &Q[(size_t)(q0 + mi * 16 + lo) * DHz + kk * 32 + hi * 8]);

  f32x4 oa[2][8] = {};
  float mcol[2] = {-1e30f, -1e30f};           // running max, q-row = lo
  float lcol[2] = {0.f, 0.f};                 // running denom, q-row = lo

  for (int kv0 = 0; kv0 < Tz; kv0 += 64) {
    // ---- S^T = K Q^T : s[mi][kvt] col=q-row(lo), rows=kv (hi*4+r) ----
    f32x4 s[2][4] = {};
#pragma unroll
    for (int kvt = 0; kvt < 4; ++kvt) {
      bf16x8 kf[4];                           // A-operand frags (rows = kv)
#pragma unroll
      for (int kk = 0; kk < 4; ++kk)
        kf[kk] = *reinterpret_cast<const bf16x8*>(
            &Kp[(size_t)(kv0 + kvt * 16 + lo) * DHz + kk * 32 + hi * 8]);
#pragma unroll
      for (int mi = 0; mi < 2; ++mi)
#pragma unroll
        for (int kk = 0; kk < 4; ++kk)
          s[mi][kvt] = __builtin_amdgcn_mfma_f32_16x16x32_bf16(
              kf[kk], qf[mi][kk], s[mi][kvt], 0, 0, 0);
    }
    // ---- online softmax (base-2), deferred rescale THR=8 (T13) ----
#pragma unroll
    for (int mi = 0; mi < 2; ++mi) {
      float tm = s[mi][0][0];
#pragma unroll
      for (int kvt = 0; kvt < 4; ++kvt)
#pragma unroll
        for (int r = 0; r < 4; ++r) tm = fmaxf(tm, s[mi][kvt][r]);
      tm = fmaxf(tm, __shfl_xor(tm, 16));
      tm = fmaxf(tm, __shfl_xor(tm, 32));     // tile max for q-row lo
      if (__any(tm > mcol[mi] + 8.f)) {       // defer-max: skip tiny rescales
        float mnew = fmaxf(mcol[mi], tm);
        float fac  = exp2f(mcol[mi] - mnew);
        mcol[mi] = mnew;
        lcol[mi] *= fac;
#pragma unroll
        for (int r = 0; r < 4; ++r) {         // fac lives at lane lo==hi*4+r
          float fr = __shfl(fac, hi * 4 + r);
#pragma unroll
          for (int nf = 0; nf < 8; ++nf) oa[mi][nf][r] *= fr;
        }
      }
      float ts = 0.f;
      const int row = mi * 16 + lo;
      const int sw  = (row & 7) << 3;         // element-XOR swizzle (8-elem)
#pragma unroll
      for (int kvt = 0; kvt < 4; ++kvt) {
        u16x4 pw;
#pragma unroll
        for (int r = 0; r < 4; ++r) {
          float p = exp2f(s[mi][kvt][r] - mcol[mi]);
          ts += p;
          pw[r] = f2bf(p);
        }
        *reinterpret_cast<u16x4*>(
            &Pl[wid][row * 64 + ((kvt * 16 + hi * 4) ^ sw)]) = pw;
      }
      ts += __shfl_xor(ts, 16);
      ts += __shfl_xor(ts, 32);
      lcol[mi] += ts;
    }
    // ---- O += P V  (P from swizzled LDS, V^T rows = Dh) ----
    bf16x8 pa[2][2];
#pragma unroll
    for (int mi = 0; mi < 2; ++mi)
#pragma unroll
      for (int kk = 0; kk < 2; ++kk) {
        int row = mi * 16 + lo;
        int c0  = (kk * 32 + hi * 8) ^ ((row & 7) << 3);
        pa[mi][kk] = *reinterpret_cast<const bf16x8*>(&Pl[wid][row * 64 + c0]);
      }
#pragma unroll
    for (int nf = 0; nf < 8; ++nf)
#pragma unroll
      for (int kk = 0; kk < 2; ++kk) {
        bf16x8 vf = *reinterpret_cast<const bf16x8*>(
            &Vp[(size_t)(nf * 16 + lo) * Tz + kv0 + kk * 32 + hi * 8]);
#pragma unroll
        for (int mi = 0; mi < 2; ++mi)
          oa[mi][nf] = __builtin_amdgcn_mfma_f32_16x16x32_bf16(
              pa[mi][kk], vf, oa[mi][nf], 0, 0, 0);
      }
  }
  // ---- epilogue: normalize, write (B,T,D) bf16 ----
  const int b = bh >> 4, h = bh & 15;
#pragma unroll
  for (int mi = 0; mi < 2; ++mi)
#pragma unroll
    for (int r = 0; r < 4; ++r) {
      float lr  = __shfl(lcol[mi], hi * 4 + r);   // denom for q-row hi*4+r
      float inv = 1.f / lr;
      int t = q0 + mi * 16 + hi * 4 + r;
#pragma unroll
      for (int nf = 0; nf < 8; ++nf)
        ob[(size_t)(b * Tz + t) * Dz + h * DHz + nf * 16 + lo] =
            f2bf(oa[mi][nf][r] * inv);
    }
}

// ---------------- launch ------------------------------------------------------
// Workspace budget note: qbuf/kbuf (2x33.5MB bf16) live INSIDE d_out (67.1MB
// fp32) — they are dead before the final O-projection GEMM fully overwrites
// d_out. d_ws use is only ~76.5MB to stay far below any plausible ws_size.
extern "C" void kernel_launch(void* const* d_in, const int* in_sizes, int n_in,
                              void* d_out, int out_size, void* d_ws, size_t ws_size,
                              hipStream_t stream) {
  const float* x  = (const float*)d_in[0];
  const float* Wq = (const float*)d_in[1];
  const float* Wk = (const float*)d_in[2];
  const float* Wv = (const float*)d_in[3];
  const float* Wo = (const float*)d_in[4];

  char* ws = (char*)d_ws;
  unsigned short* xb    = (unsigned short*)(ws);              // 33.5MB, reused as attn out
  unsigned short* wslot = (unsigned short*)(ws + 33554432);   // 8.4MB (one converted W)
  unsigned short* vtb   = (unsigned short*)(ws + 41943040);   // 33.5MB (B,H,Dh,T)
  float* cosv = (float*)(ws + 75497472);                      // 512KB
  float* sinv = (float*)(ws + 76021760);                      // 512KB (end: 76.5MB)
  // q/k tensors inside d_out (67.1MB = exactly 2x 33.5MB)
  unsigned short* qbuf  = (unsigned short*)d_out;             // (B,H,T,Dh) bf16
  unsigned short* kbuf  = (unsigned short*)d_out + (size_t)Mz * Dz; // (B,H,T,Dh)

  rope_tab<<<512, 256, 0, stream>>>(cosv, sinv);
  cvt_bf16<<<16384, 256, 0, stream>>>(x, xb, Mz * Dz / 4);

  cvt_bf16<<<4096, 256, 0, stream>>>(Wq, wslot, Dz * Dz / 4);
  gemm_bt<1><<<1024, 256, 0, stream>>>(xb, wslot, qbuf);
  cvt_bf16<<<4096, 256, 0, stream>>>(Wk, wslot, Dz * Dz / 4);
  gemm_bt<1><<<1024, 256, 0, stream>>>(xb, wslot, kbuf);
  cvt_bf16<<<4096, 256, 0, stream>>>(Wv, wslot, Dz * Dz / 4);
  gemm_bt<2><<<1024, 256, 0, stream>>>(xb, wslot, vtb);

  // q gets log2(e)/sqrt(Dh) folded in (base-2 softmax); k unscaled
  rope_apply<<<4096, 256, 0, stream>>>(qbuf, cosv, sinv, 0.12751744900783237f);
  rope_apply<<<4096, 256, 0, stream>>>(kbuf, cosv, sinv, 1.0f);

  attn_fwd<<<1024, 256, 0, stream>>>(qbuf, kbuf, vtb, xb);

  cvt_bf16<<<4096, 256, 0, stream>>>(Wo, wslot, Dz * Dz / 4);
  gemm_bt<0><<<1024, 256, 0, stream>>>(xb, wslot, (float*)d_out);
}

// Round 9
// 884.825 us; speedup vs baseline: 1.1875x; 1.1875x over previous
//
#include <hip/hip_runtime.h>
#include <stdint.h>
#include <stddef.h>

// Problem constants
#define Bz  4
#define Tz  2048
#define Dz  2048
#define Hz  16
#define DHz 128
#define Mz  (Bz * Tz)   // 8192 rows

typedef __attribute__((ext_vector_type(4))) float  f32x4;
typedef __attribute__((ext_vector_type(8))) __bf16 bf16x8;   // 4 VGPRs = MFMA A/B frag
typedef __attribute__((ext_vector_type(8))) unsigned short u16x8;
typedef __attribute__((ext_vector_type(4))) unsigned short u16x4;

__device__ __forceinline__ unsigned short f2bf(float f) {
  union { float f; unsigned int u; } a; a.f = f;
  unsigned int u = a.u;
  u += 0x7FFFu + ((u >> 16) & 1u);            // round-to-nearest-even
  return (unsigned short)(u >> 16);
}
__device__ __forceinline__ float bf2f(unsigned short s) {
  union { unsigned int u; float f; } a; a.u = ((unsigned int)s) << 16;
  return a.f;
}
// async global->LDS, 16B per lane. LDS dest must be wave-uniform + lane*16.
__device__ __forceinline__ void load_lds16(const void* g, void* l) {
  __builtin_amdgcn_global_load_lds(
      (const __attribute__((address_space(1))) unsigned int*)g,
      (__attribute__((address_space(3))) unsigned int*)l, 16, 0, 0);
}

// ---------------- fp32 -> bf16 convert (4 elems/thread, vectorized) ----------
__global__ __launch_bounds__(256) void cvt_bf16(const float* __restrict__ in,
                         unsigned short* __restrict__ out, int n4) {
  int i = blockIdx.x * 256 + threadIdx.x;
  if (i >= n4) return;
  float4 v = reinterpret_cast<const float4*>(in)[i];
  ushort4 o;
  o.x = f2bf(v.x); o.y = f2bf(v.y); o.z = f2bf(v.z); o.w = f2bf(v.w);
  reinterpret_cast<ushort4*>(out)[i] = o;
}

// ---------------- RoPE tables: cos/sin[t][j], j in [0,64) --------------------
__global__ __launch_bounds__(256) void rope_tab(float* __restrict__ cosv,
                                                float* __restrict__ sinv) {
  int i = blockIdx.x * 256 + threadIdx.x;      // 0 .. 131071
  int t = i >> 6, j = i & 63;
  // theta_j = 10000^(-j/64) = exp(-j * ln(10000)/64)
  float theta = __expf(-(float)j * (9.210340371976184f / 64.0f));
  float ang = (float)t * theta;
  cosv[i] = cosf(ang);
  sinv[i] = sinf(ang);
}

// ---------------- RoPE apply (in-place on (B,H,T,Dh) bf16), fused q-scale ----
// out_lo = x_lo*cos - x_hi*sin ; out_hi = x_hi*cos + x_lo*sin  (rotate_half)
__global__ __launch_bounds__(256) void rope_apply(unsigned short* __restrict__ x,
                           const float* __restrict__ cosv,
                           const float* __restrict__ sinv, float scale) {
  int gid = blockIdx.x * 256 + threadIdx.x;    // B*H*T*8 = 1,048,576
  int row = gid >> 3, c = gid & 7;
  int t = row & (Tz - 1);
  int d0 = c * 8;
  unsigned short* pl = x + (size_t)row * DHz + d0;
  unsigned short* ph = pl + 64;
  u16x8 lo8 = *reinterpret_cast<const u16x8*>(pl);
  u16x8 hi8 = *reinterpret_cast<const u16x8*>(ph);
  const float* ct = cosv + t * 64 + d0;
  const float* st = sinv + t * 64 + d0;
  float4 ca = *reinterpret_cast<const float4*>(ct);
  float4 cb = *reinterpret_cast<const float4*>(ct + 4);
  float4 sa = *reinterpret_cast<const float4*>(st);
  float4 sb = *reinterpret_cast<const float4*>(st + 4);
  float cc[8] = {ca.x, ca.y, ca.z, ca.w, cb.x, cb.y, cb.z, cb.w};
  float ss[8] = {sa.x, sa.y, sa.z, sa.w, sb.x, sb.y, sb.z, sb.w};
  u16x8 nl, nh;
#pragma unroll
  for (int j = 0; j < 8; ++j) {
    float xl = bf2f(lo8[j]), xh = bf2f(hi8[j]);
    nl[j] = f2bf((xl * cc[j] - xh * ss[j]) * scale);
    nh[j] = f2bf((xh * cc[j] + xl * ss[j]) * scale);
  }
  *reinterpret_cast<u16x8*>(pl) = nl;
  *reinterpret_cast<u16x8*>(ph) = nh;
}

// ---------------- NT GEMM: out = A(M,K) * Bw(N,K)^T, bf16 in / fp32 acc ------
// m97 structure: 128x128 tile, 4 waves (2x2), BK=64, global_load_lds width 16.
// 1D grid of 1024 blocks with XCD-aware swizzle (T1; 1024%8==0 -> bijective).
// MODE 0: fp32 out, row-major (M,N)
// MODE 1: bf16 out scattered to (B,H,T,Dh)
// MODE 2: bf16 out scattered to (B,H,Dh,T)  (transposed V for attention)
template <int MODE>
__global__ __launch_bounds__(256)
void gemm_bt(const unsigned short* __restrict__ A,
             const unsigned short* __restrict__ Bw,
             void* __restrict__ outp) {
  __shared__ unsigned short Al[128 * 64];
  __shared__ unsigned short Bl[128 * 64];
  const int tid  = threadIdx.x;
  const int lane = tid & 63, wid = tid >> 6;
  const int wr = wid >> 1, wc = wid & 1;
  const int lo = lane & 15, hi = lane >> 4;
  const int w  = (blockIdx.x & 7) * 128 + (blockIdx.x >> 3);  // XCD swizzle
  const int n0 = (w & 15) * 128;
  const int m0 = (w >> 4) * 128;
  f32x4 acc[4][4] = {};

  for (int k0 = 0; k0 < Dz; k0 += 64) {
#pragma unroll
    for (int i = 0; i < 4; ++i) {
      int idx = i * 256 + tid;          // 1024 chunks of 8 bf16 (16B)
      int row = idx >> 3, ch = idx & 7;
      load_lds16(A  + (size_t)(m0 + row) * Dz + k0 + ch * 8, &Al[idx * 8]);
      load_lds16(Bw + (size_t)(n0 + row) * Dz + k0 + ch * 8, &Bl[idx * 8]);
    }
    __syncthreads();
#pragma unroll
    for (int kk = 0; kk < 2; ++kk) {
      bf16x8 a[4], b[4];
#pragma unroll
      for (int mi = 0; mi < 4; ++mi)
        a[mi] = *reinterpret_cast<const bf16x8*>(
            &Al[(wr * 64 + mi * 16 + lo) * 64 + kk * 32 + hi * 8]);
#pragma unroll
      for (int ni = 0; ni < 4; ++ni)
        b[ni] = *reinterpret_cast<const bf16x8*>(
            &Bl[(wc * 64 + ni * 16 + lo) * 64 + kk * 32 + hi * 8]);
#pragma unroll
      for (int mi = 0; mi < 4; ++mi)
#pragma unroll
        for (int ni = 0; ni < 4; ++ni)
          acc[mi][ni] = __builtin_amdgcn_mfma_f32_16x16x32_bf16(
              a[mi], b[ni], acc[mi][ni], 0, 0, 0);
    }
    __syncthreads();
  }

#pragma unroll
  for (int mi = 0; mi < 4; ++mi)
#pragma unroll
    for (int ni = 0; ni < 4; ++ni)
#pragma unroll
      for (int r = 0; r < 4; ++r) {
        // verified C/D layout: col = lane&15 (B-row), row = (lane>>4)*4 + r
        int m = m0 + wr * 64 + mi * 16 + hi * 4 + r;
        int n = n0 + wc * 64 + ni * 16 + lo;
        float v = acc[mi][ni][r];
        if (MODE == 0) {
          reinterpret_cast<float*>(outp)[(size_t)m * Dz + n] = v;
        } else if (MODE == 1) {
          int b = m >> 11, t = m & (Tz - 1);
          int h = n >> 7,  d = n & (DHz - 1);
          reinterpret_cast<unsigned short*>(outp)
              [((size_t)(b * Hz + h) * Tz + t) * DHz + d] = f2bf(v);
        } else {
          int b = m >> 11, t = m & (Tz - 1);
          int h = n >> 7,  d = n & (DHz - 1);
          reinterpret_cast<unsigned short*>(outp)
              [((size_t)(b * Hz + h) * DHz + d) * Tz + t] = f2bf(v);
        }
      }
}

// ---------------- Flash attention, bf16 MFMA 16x16x32 ------------------------
// R6 change (latency-bound fix, MfmaUtil 11.5%): cooperative K/V LDS staging,
// double-buffered, ONE __syncthreads per KV tile (T3 minimum-2-phase):
//   stage(buf^1, tile t+1)  ->  compute from buf  ->  syncthreads (drains vmcnt)
// K-tile 64x128 and V^T-tile 128x64 staged via global_load_lds with the
// rule-#21 pattern: LINEAR LDS dest + pre-swizzled GLOBAL source chunk
// (chunk ^= row&7, 16B granularity) + same XOR on the ds_read side ->
// conflict-free b128 frag reads (8 lanes per bank-quad = wave floor).
// Shares each K/V tile across all 4 waves (was: 4x redundant global loads).
__global__ __launch_bounds__(256)
void attn_fwd(const unsigned short* __restrict__ qb,
              const unsigned short* __restrict__ kb,
              const unsigned short* __restrict__ vt,
              unsigned short* __restrict__ ob) {
  __shared__ unsigned short Kl[2][64 * 128];  // 32KB: K tile [kv][d], dbuf
  __shared__ unsigned short Vl[2][128 * 64];  // 32KB: V^T tile [d][kv], dbuf
  __shared__ unsigned short Pl[4][32 * 64];   // 16KB: per-wave P, XOR-swizzled
  const int tid  = threadIdx.x;
  const int lane = tid & 63, wid = tid >> 6;
  const int lo = lane & 15, hi = lane >> 4;
  const int w  = (blockIdx.x & 7) * 128 + (blockIdx.x >> 3);  // XCD swizzle
  const int bh = w >> 4;
  const int q0 = (w & 15) * 128 + wid * 32;
  const size_t base = (size_t)bh * Tz * DHz;
  const unsigned short* Q  = qb + base;
  const unsigned short* Kp = kb + base;
  const unsigned short* Vp = vt + base;       // [Dh][T] per head

  bf16x8 qf[2][4];                            // B-operand frags (rows = q)
#pragma unroll
  for (int mi = 0; mi < 2; ++mi)
#pragma unroll
    for (int kk = 0; kk < 4; ++kk)
      qf[mi][kk] = *reinterpret_cast<const bf16x8*>(
          &Q[(size_t)(q0 + mi * 16 + lo) * DHz + kk * 32 + hi * 8]);

  f32x4 oa[2][8] = {};
  float mcol[2] = {-1e30f, -1e30f};           // running max, q-row = lo
  float lcol[2] = {0.f, 0.f};                 // running denom, q-row = lo

  // ---- prologue: stage tile 0 into buffer 0 ----
#pragma unroll
  for (int i = 0; i < 4; ++i) {               // K: 1024 chunks, 16/row
    int idx = i * 256 + tid, row = idx >> 4, ch = idx & 15;
    load_lds16(Kp + (size_t)row * DHz + (ch ^ (row & 7)) * 8, &Kl[0][idx * 8]);
  }
#pragma unroll
  for (int i = 0; i < 4; ++i) {               // V^T: 1024 chunks, 8/row
    int idx = i * 256 + tid, row = idx >> 3, ch = idx & 7;
    load_lds16(Vp + (size_t)row * Tz + (ch ^ (row & 7)) * 8, &Vl[0][idx * 8]);
  }
  __syncthreads();                            // drains vmcnt(0)

  int cur = 0;
  for (int it = 0; it < Tz / 64; ++it) {
    // ---- issue next tile's staging (overlaps with compute below) ----
    if (it + 1 < Tz / 64) {
      const int kvn = (it + 1) * 64;
#pragma unroll
      for (int i = 0; i < 4; ++i) {
        int idx = i * 256 + tid, row = idx >> 4, ch = idx & 15;
        load_lds16(Kp + (size_t)(kvn + row) * DHz + (ch ^ (row & 7)) * 8,
                   &Kl[cur ^ 1][idx * 8]);
      }
#pragma unroll
      for (int i = 0; i < 4; ++i) {
        int idx = i * 256 + tid, row = idx >> 3, ch = idx & 7;
        load_lds16(Vp + (size_t)row * Tz + kvn + (ch ^ (row & 7)) * 8,
                   &Vl[cur ^ 1][idx * 8]);
      }
    }
    const unsigned short* Kc = &Kl[cur][0];
    const unsigned short* Vc = &Vl[cur][0];

    // ---- S^T = K Q^T : s[mi][kvt] col=q-row(lo), rows=kv (hi*4+r) ----
    f32x4 s[2][4] = {};
#pragma unroll
    for (int kvt = 0; kvt < 4; ++kvt) {
      bf16x8 kf[4];                           // A-operand frags (rows = kv)
#pragma unroll
      for (int kk = 0; kk < 4; ++kk) {
        int row = kvt * 16 + lo;
        kf[kk] = *reinterpret_cast<const bf16x8*>(
            &Kc[row * 128 + (((kk * 4 + hi) ^ (row & 7)) * 8)]);
      }
#pragma unroll
      for (int mi = 0; mi < 2; ++mi)
#pragma unroll
        for (int kk = 0; kk < 4; ++kk)
          s[mi][kvt] = __builtin_amdgcn_mfma_f32_16x16x32_bf16(
              kf[kk], qf[mi][kk], s[mi][kvt], 0, 0, 0);
    }
    // ---- online softmax (base-2), deferred rescale THR=8 (T13) ----
#pragma unroll
    for (int mi = 0; mi < 2; ++mi) {
      float tm = s[mi][0][0];
#pragma unroll
      for (int kvt = 0; kvt < 4; ++kvt)
#pragma unroll
        for (int r = 0; r < 4; ++r) tm = fmaxf(tm, s[mi][kvt][r]);
      tm = fmaxf(tm, __shfl_xor(tm, 16));
      tm = fmaxf(tm, __shfl_xor(tm, 32));     // tile max for q-row lo
      if (__any(tm > mcol[mi] + 8.f)) {       // defer-max: skip tiny rescales
        float mnew = fmaxf(mcol[mi], tm);
        float fac  = exp2f(mcol[mi] - mnew);
        mcol[mi] = mnew;
        lcol[mi] *= fac;
#pragma unroll
        for (int r = 0; r < 4; ++r) {         // fac lives at lane lo==hi*4+r
          float fr = __shfl(fac, hi * 4 + r);
#pragma unroll
          for (int nf = 0; nf < 8; ++nf) oa[mi][nf][r] *= fr;
        }
      }
      float ts = 0.f;
      const int row = mi * 16 + lo;
      const int sw  = (row & 7) << 3;         // element-XOR swizzle (8-elem)
#pragma unroll
      for (int kvt = 0; kvt < 4; ++kvt) {
        u16x4 pw;
#pragma unroll
        for (int r = 0; r < 4; ++r) {
          float p = exp2f(s[mi][kvt][r] - mcol[mi]);
          ts += p;
          pw[r] = f2bf(p);
        }
        *reinterpret_cast<u16x4*>(
            &Pl[wid][row * 64 + ((kvt * 16 + hi * 4) ^ sw)]) = pw;
      }
      ts += __shfl_xor(ts, 16);
      ts += __shfl_xor(ts, 32);
      lcol[mi] += ts;
    }
    // ---- O += P V  (P from swizzled LDS, V^T tile rows = Dh) ----
    bf16x8 pa[2][2];
#pragma unroll
    for (int mi = 0; mi < 2; ++mi)
#pragma unroll
      for (int kk = 0; kk < 2; ++kk) {
        int row = mi * 16 + lo;
        int c0  = (kk * 32 + hi * 8) ^ ((row & 7) << 3);
        pa[mi][kk] = *reinterpret_cast<const bf16x8*>(&Pl[wid][row * 64 + c0]);
      }
#pragma unroll
    for (int nf = 0; nf < 8; ++nf) {
      int row = nf * 16 + lo;
#pragma unroll
      for (int kk = 0; kk < 2; ++kk) {
        bf16x8 vf = *reinterpret_cast<const bf16x8*>(
            &Vc[row * 64 + (((kk * 4 + hi) ^ (row & 7)) * 8)]);
#pragma unroll
        for (int mi = 0; mi < 2; ++mi)
          oa[mi][nf] = __builtin_amdgcn_mfma_f32_16x16x32_bf16(
              pa[mi][kk], vf, oa[mi][nf], 0, 0, 0);
      }
    }
    __syncthreads();   // staged tile ready; all waves done with buffer `cur`
    cur ^= 1;
  }
  // ---- epilogue: normalize, write (B,T,D) bf16 ----
  const int b = bh >> 4, h = bh & 15;
#pragma unroll
  for (int mi = 0; mi < 2; ++mi)
#pragma unroll
    for (int r = 0; r < 4; ++r) {
      float lr  = __shfl(lcol[mi], hi * 4 + r);   // denom for q-row hi*4+r
      float inv = 1.f / lr;
      int t = q0 + mi * 16 + hi * 4 + r;
#pragma unroll
      for (int nf = 0; nf < 8; ++nf)
        ob[(size_t)(b * Tz + t) * Dz + h * DHz + nf * 16 + lo] =
            f2bf(oa[mi][nf][r] * inv);
    }
}

// ---------------- launch ------------------------------------------------------
// Workspace budget note: qbuf/kbuf (2x33.5MB bf16) live INSIDE d_out (67.1MB
// fp32) — they are dead before the final O-projection GEMM fully overwrites
// d_out. d_ws use is only ~76.5MB.
extern "C" void kernel_launch(void* const* d_in, const int* in_sizes, int n_in,
                              void* d_out, int out_size, void* d_ws, size_t ws_size,
                              hipStream_t stream) {
  const float* x  = (const float*)d_in[0];
  const float* Wq = (const float*)d_in[1];
  const float* Wk = (const float*)d_in[2];
  const float* Wv = (const float*)d_in[3];
  const float* Wo = (const float*)d_in[4];

  char* ws = (char*)d_ws;
  unsigned short* xb    = (unsigned short*)(ws);              // 33.5MB, reused as attn out
  unsigned short* wslot = (unsigned short*)(ws + 33554432);   // 8.4MB (one converted W)
  unsigned short* vtb   = (unsigned short*)(ws + 41943040);   // 33.5MB (B,H,Dh,T)
  float* cosv = (float*)(ws + 75497472);                      // 512KB
  float* sinv = (float*)(ws + 76021760);                      // 512KB (end: 76.5MB)
  // q/k tensors inside d_out (67.1MB = exactly 2x 33.5MB)
  unsigned short* qbuf  = (unsigned short*)d_out;             // (B,H,T,Dh) bf16
  unsigned short* kbuf  = (unsigned short*)d_out + (size_t)Mz * Dz; // (B,H,T,Dh)

  rope_tab<<<512, 256, 0, stream>>>(cosv, sinv);
  cvt_bf16<<<16384, 256, 0, stream>>>(x, xb, Mz * Dz / 4);

  cvt_bf16<<<4096, 256, 0, stream>>>(Wq, wslot, Dz * Dz / 4);
  gemm_bt<1><<<1024, 256, 0, stream>>>(xb, wslot, qbuf);
  cvt_bf16<<<4096, 256, 0, stream>>>(Wk, wslot, Dz * Dz / 4);
  gemm_bt<1><<<1024, 256, 0, stream>>>(xb, wslot, kbuf);
  cvt_bf16<<<4096, 256, 0, stream>>>(Wv, wslot, Dz * Dz / 4);
  gemm_bt<2><<<1024, 256, 0, stream>>>(xb, wslot, vtb);

  // q gets log2(e)/sqrt(Dh) folded in (base-2 softmax); k unscaled
  rope_apply<<<4096, 256, 0, stream>>>(qbuf, cosv, sinv, 0.12751744900783237f);
  rope_apply<<<4096, 256, 0, stream>>>(kbuf, cosv, sinv, 1.0f);

  attn_fwd<<<1024, 256, 0, stream>>>(qbuf, kbuf, vtb, xb);

  cvt_bf16<<<4096, 256, 0, stream>>>(Wo, wslot, Dz * Dz / 4);
  gemm_bt<0><<<1024, 256, 0, stream>>>(xb, wslot, (float*)d_out);
}

// Round 11
// 828.634 us; speedup vs baseline: 1.2681x; 1.0678x over previous
//
#include <hip/hip_runtime.h>
#include <stdint.h>
#include <stddef.h>

// Problem constants
#define Bz  4
#define Tz  2048
#define Dz  2048
#define Hz  16
#define DHz 128
#define Mz  (Bz * Tz)   // 8192 rows

typedef __attribute__((ext_vector_type(4))) float  f32x4;
typedef __attribute__((ext_vector_type(8))) __bf16 bf16x8;   // 4 VGPRs = MFMA A/B frag
typedef __attribute__((ext_vector_type(8))) unsigned short u16x8;
typedef __attribute__((ext_vector_type(4))) unsigned short u16x4;

__device__ __forceinline__ unsigned short f2bf(float f) {
  union { float f; unsigned int u; } a; a.f = f;
  unsigned int u = a.u;
  u += 0x7FFFu + ((u >> 16) & 1u);            // round-to-nearest-even
  return (unsigned short)(u >> 16);
}
__device__ __forceinline__ float bf2f(unsigned short s) {
  union { unsigned int u; float f; } a; a.u = ((unsigned int)s) << 16;
  return a.f;
}
// async global->LDS, 16B per lane. LDS dest must be wave-uniform + lane*16.
__device__ __forceinline__ void load_lds16(const void* g, void* l) {
  __builtin_amdgcn_global_load_lds(
      (const __attribute__((address_space(1))) unsigned int*)g,
      (__attribute__((address_space(3))) unsigned int*)l, 16, 0, 0);
}

// ---------------- fp32 -> bf16 convert (4 elems/thread, vectorized) ----------
__global__ __launch_bounds__(256) void cvt_bf16(const float* __restrict__ in,
                         unsigned short* __restrict__ out, int n4) {
  int i = blockIdx.x * 256 + threadIdx.x;
  if (i >= n4) return;
  float4 v = reinterpret_cast<const float4*>(in)[i];
  ushort4 o;
  o.x = f2bf(v.x); o.y = f2bf(v.y); o.z = f2bf(v.z); o.w = f2bf(v.w);
  reinterpret_cast<ushort4*>(out)[i] = o;
}

// ---------------- RoPE tables: cos/sin[t][j], j in [0,64) --------------------
__global__ __launch_bounds__(256) void rope_tab(float* __restrict__ cosv,
                                                float* __restrict__ sinv) {
  int i = blockIdx.x * 256 + threadIdx.x;      // 0 .. 131071
  int t = i >> 6, j = i & 63;
  // theta_j = 10000^(-j/64) = exp(-j * ln(10000)/64)
  float theta = __expf(-(float)j * (9.210340371976184f / 64.0f));
  float ang = (float)t * theta;
  cosv[i] = cosf(ang);
  sinv[i] = sinf(ang);
}

// ---------------- RoPE apply (in-place on (B,H,T,Dh) bf16), fused q-scale ----
// out_lo = x_lo*cos - x_hi*sin ; out_hi = x_hi*cos + x_lo*sin  (rotate_half)
__global__ __launch_bounds__(256) void rope_apply(unsigned short* __restrict__ x,
                           const float* __restrict__ cosv,
                           const float* __restrict__ sinv, float scale) {
  int gid = blockIdx.x * 256 + threadIdx.x;    // B*H*T*8 = 1,048,576
  int row = gid >> 3, c = gid & 7;
  int t = row & (Tz - 1);
  int d0 = c * 8;
  unsigned short* pl = x + (size_t)row * DHz + d0;
  unsigned short* ph = pl + 64;
  u16x8 lo8 = *reinterpret_cast<const u16x8*>(pl);
  u16x8 hi8 = *reinterpret_cast<const u16x8*>(ph);
  const float* ct = cosv + t * 64 + d0;
  const float* st = sinv + t * 64 + d0;
  float4 ca = *reinterpret_cast<const float4*>(ct);
  float4 cb = *reinterpret_cast<const float4*>(ct + 4);
  float4 sa = *reinterpret_cast<const float4*>(st);
  float4 sb = *reinterpret_cast<const float4*>(st + 4);
  float cc[8] = {ca.x, ca.y, ca.z, ca.w, cb.x, cb.y, cb.z, cb.w};
  float ss[8] = {sa.x, sa.y, sa.z, sa.w, sb.x, sb.y, sb.z, sb.w};
  u16x8 nl, nh;
#pragma unroll
  for (int j = 0; j < 8; ++j) {
    float xl = bf2f(lo8[j]), xh = bf2f(hi8[j]);
    nl[j] = f2bf((xl * cc[j] - xh * ss[j]) * scale);
    nh[j] = f2bf((xh * cc[j] + xl * ss[j]) * scale);
  }
  *reinterpret_cast<u16x8*>(pl) = nl;
  *reinterpret_cast<u16x8*>(ph) = nh;
}

// ---------------- NT GEMM: out = A(M,K) * Bw(N,K)^T, bf16 in / fp32 acc ------
// m97 structure: 128x128 tile, 4 waves (2x2), BK=64, global_load_lds width 16.
// 1D grid of 1024 blocks with XCD-aware swizzle (T1; 1024%8==0 -> bijective).
// MODE 0: fp32 out, row-major (M,N)
// MODE 1: bf16 out scattered to (B,H,T,Dh)
// MODE 2: bf16 out scattered to (B,H,Dh,T)  (transposed V for attention)
template <int MODE>
__global__ __launch_bounds__(256)
void gemm_bt(const unsigned short* __restrict__ A,
             const unsigned short* __restrict__ Bw,
             void* __restrict__ outp) {
  __shared__ unsigned short Al[128 * 64];
  __shared__ unsigned short Bl[128 * 64];
  const int tid  = threadIdx.x;
  const int lane = tid & 63, wid = tid >> 6;
  const int wr = wid >> 1, wc = wid & 1;
  const int lo = lane & 15, hi = lane >> 4;
  const int w  = (blockIdx.x & 7) * 128 + (blockIdx.x >> 3);  // XCD swizzle
  const int n0 = (w & 15) * 128;
  const int m0 = (w >> 4) * 128;
  f32x4 acc[4][4] = {};

  for (int k0 = 0; k0 < Dz; k0 += 64) {
#pragma unroll
    for (int i = 0; i < 4; ++i) {
      int idx = i * 256 + tid;          // 1024 chunks of 8 bf16 (16B)
      int row = idx >> 3, ch = idx & 7;
      load_lds16(A  + (size_t)(m0 + row) * Dz + k0 + ch * 8, &Al[idx * 8]);
      load_lds16(Bw + (size_t)(n0 + row) * Dz + k0 + ch * 8, &Bl[idx * 8]);
    }
    __syncthreads();
#pragma unroll
    for (int kk = 0; kk < 2; ++kk) {
      bf16x8 a[4], b[4];
#pragma unroll
      for (int mi = 0; mi < 4; ++mi)
        a[mi] = *reinterpret_cast<const bf16x8*>(
            &Al[(wr * 64 + mi * 16 + lo) * 64 + kk * 32 + hi * 8]);
#pragma unroll
      for (int ni = 0; ni < 4; ++ni)
        b[ni] = *reinterpret_cast<const bf16x8*>(
            &Bl[(wc * 64 + ni * 16 + lo) * 64 + kk * 32 + hi * 8]);
#pragma unroll
      for (int mi = 0; mi < 4; ++mi)
#pragma unroll
        for (int ni = 0; ni < 4; ++ni)
          acc[mi][ni] = __builtin_amdgcn_mfma_f32_16x16x32_bf16(
              a[mi], b[ni], acc[mi][ni], 0, 0, 0);
    }
    __syncthreads();
  }

#pragma unroll
  for (int mi = 0; mi < 4; ++mi)
#pragma unroll
    for (int ni = 0; ni < 4; ++ni)
#pragma unroll
      for (int r = 0; r < 4; ++r) {
        // verified C/D layout: col = lane&15 (B-row), row = (lane>>4)*4 + r
        int m = m0 + wr * 64 + mi * 16 + hi * 4 + r;
        int n = n0 + wc * 64 + ni * 16 + lo;
        float v = acc[mi][ni][r];
        if (MODE == 0) {
          reinterpret_cast<float*>(outp)[(size_t)m * Dz + n] = v;
        } else if (MODE == 1) {
          int b = m >> 11, t = m & (Tz - 1);
          int h = n >> 7,  d = n & (DHz - 1);
          reinterpret_cast<unsigned short*>(outp)
              [((size_t)(b * Hz + h) * Tz + t) * DHz + d] = f2bf(v);
        } else {
          int b = m >> 11, t = m & (Tz - 1);
          int h = n >> 7,  d = n & (DHz - 1);
          reinterpret_cast<unsigned short*>(outp)
              [((size_t)(b * Hz + h) * DHz + d) * Tz + t] = f2bf(v);
        }
      }
}

// ---------------- Flash attention, bf16 MFMA 16x16x32 ------------------------
// R10/R11 (occupancy fix; R9 showed 80KB LDS -> 1 block/CU, Occ 11.7%):
// KVBLK 64 -> 32. LDS 48KB (K 2x8K dbuf, V^T 2x8K dbuf, P 16K) -> 3 blocks/CU
// (144KB LDS, 3x132 VGPR <= 512/SIMD). Same verified 2-phase dbuf schedule:
//   stage(buf^1, tile t+1) -> compute from buf -> __syncthreads (drains vmcnt)
// Swizzles re-derived for KVBLK=32 (desk-checked twice):
//  - K stage: 16 chunks/row, ch ^ (row&7)  (4-bit chunk space, ok)
//  - V stage:  4 chunks/row, ch ^ (row&3)  (2-bit chunk space — &7 would
//    index outside the 32-kv tile)
//  - P keeps row-stride 64 so col^sw stays in-row (stride-32 would overflow)
__global__ __launch_bounds__(256)
void attn_fwd(const unsigned short* __restrict__ qb,
              const unsigned short* __restrict__ kb,
              const unsigned short* __restrict__ vt,
              unsigned short* __restrict__ ob) {
  __shared__ unsigned short Kl[2][32 * 128];  // 16KB: K tile [kv][d], dbuf
  __shared__ unsigned short Vl[2][128 * 32];  // 16KB: V^T tile [d][kv], dbuf
  __shared__ unsigned short Pl[4][32 * 64];   // 16KB: per-wave P, XOR-swizzled
  const int tid  = threadIdx.x;
  const int lane = tid & 63, wid = tid >> 6;
  const int lo = lane & 15, hi = lane >> 4;
  const int w  = (blockIdx.x & 7) * 128 + (blockIdx.x >> 3);  // XCD swizzle
  const int bh = w >> 4;
  const int q0 = (w & 15) * 128 + wid * 32;
  const size_t base = (size_t)bh * Tz * DHz;
  const unsigned short* Q  = qb + base;
  const unsigned short* Kp = kb + base;
  const unsigned short* Vp = vt + base;       // [Dh][T] per head

  bf16x8 qf[2][4];                            // B-operand frags (rows = q)
#pragma unroll
  for (int mi = 0; mi < 2; ++mi)
#pragma unroll
    for (int kk = 0; kk < 4; ++kk)
      qf[mi][kk] = *reinterpret_cast<const bf16x8*>(
          &Q[(size_t)(q0 + mi * 16 + lo) * DHz + kk * 32 + hi * 8]);

  f32x4 oa[2][8] = {};
  float mcol[2] = {-1e30f, -1e30f};           // running max, q-row = lo
  float lcol[2] = {0.f, 0.f};                 // running denom, q-row = lo

  // ---- prologue: stage tile 0 into buffer 0 ----
#pragma unroll
  for (int i = 0; i < 2; ++i) {               // K: 512 chunks, 16/row
    int idx = i * 256 + tid, row = idx >> 4, ch = idx & 15;
    load_lds16(Kp + (size_t)row * DHz + (ch ^ (row & 7)) * 8, &Kl[0][idx * 8]);
  }
#pragma unroll
  for (int i = 0; i < 2; ++i) {               // V^T: 512 chunks, 4/row
    int idx = i * 256 + tid, row = idx >> 2, ch = idx & 3;
    load_lds16(Vp + (size_t)row * Tz + (ch ^ (row & 3)) * 8, &Vl[0][idx * 8]);
  }
  __syncthreads();                            // drains vmcnt(0)

  int cur = 0;
  for (int it = 0; it < Tz / 32; ++it) {
    // ---- issue next tile's staging (overlaps with compute below) ----
    if (it + 1 < Tz / 32) {
      const int kvn = (it + 1) * 32;
#pragma unroll
      for (int i = 0; i < 2; ++i) {
        int idx = i * 256 + tid, row = idx >> 4, ch = idx & 15;
        load_lds16(Kp + (size_t)(kvn + row) * DHz + (ch ^ (row & 7)) * 8,
                   &Kl[cur ^ 1][idx * 8]);
      }
#pragma unroll
      for (int i = 0; i < 2; ++i) {
        int idx = i * 256 + tid, row = idx >> 2, ch = idx & 3;
        load_lds16(Vp + (size_t)row * Tz + kvn + (ch ^ (row & 3)) * 8,
                   &Vl[cur ^ 1][idx * 8]);
      }
    }
    const unsigned short* Kc = &Kl[cur][0];
    const unsigned short* Vc = &Vl[cur][0];

    // ---- S^T = K Q^T : s[mi][kvt] col=q-row(lo), rows=kv (hi*4+r) ----
    f32x4 s[2][2] = {};
#pragma unroll
    for (int kvt = 0; kvt < 2; ++kvt) {
      bf16x8 kf[4];                           // A-operand frags (rows = kv)
#pragma unroll
      for (int kk = 0; kk < 4; ++kk) {
        int row = kvt * 16 + lo;
        kf[kk] = *reinterpret_cast<const bf16x8*>(
            &Kc[row * 128 + (((kk * 4 + hi) ^ (row & 7)) * 8)]);
      }
#pragma unroll
      for (int mi = 0; mi < 2; ++mi)
#pragma unroll
        for (int kk = 0; kk < 4; ++kk)
          s[mi][kvt] = __builtin_amdgcn_mfma_f32_16x16x32_bf16(
              kf[kk], qf[mi][kk], s[mi][kvt], 0, 0, 0);
    }
    // ---- online softmax (base-2), deferred rescale THR=8 (T13) ----
#pragma unroll
    for (int mi = 0; mi < 2; ++mi) {
      float tm = s[mi][0][0];
#pragma unroll
      for (int kvt = 0; kvt < 2; ++kvt)
#pragma unroll
        for (int r = 0; r < 4; ++r) tm = fmaxf(tm, s[mi][kvt][r]);
      tm = fmaxf(tm, __shfl_xor(tm, 16));
      tm = fmaxf(tm, __shfl_xor(tm, 32));     // tile max for q-row lo
      if (__any(tm > mcol[mi] + 8.f)) {       // defer-max: skip tiny rescales
        float mnew = fmaxf(mcol[mi], tm);
        float fac  = exp2f(mcol[mi] - mnew);
        mcol[mi] = mnew;
        lcol[mi] *= fac;
#pragma unroll
        for (int r = 0; r < 4; ++r) {         // fac lives at lane lo==hi*4+r
          float fr = __shfl(fac, hi * 4 + r);
#pragma unroll
          for (int nf = 0; nf < 8; ++nf) oa[mi][nf][r] *= fr;
        }
      }
      float ts = 0.f;
      const int row = mi * 16 + lo;
      const int sw  = (row & 7) << 3;         // element-XOR swizzle (8-elem)
#pragma unroll
      for (int kvt = 0; kvt < 2; ++kvt) {
        u16x4 pw;
#pragma unroll
        for (int r = 0; r < 4; ++r) {
          float p = exp2f(s[mi][kvt][r] - mcol[mi]);
          ts += p;
          pw[r] = f2bf(p);
        }
        *reinterpret_cast<u16x4*>(
            &Pl[wid][row * 64 + ((kvt * 16 + hi * 4) ^ sw)]) = pw;
      }
      ts += __shfl_xor(ts, 16);
      ts += __shfl_xor(ts, 32);
      lcol[mi] += ts;
    }
    // ---- O += P V  (P from swizzled LDS, V^T tile rows = Dh) ----
    bf16x8 pa[2];
#pragma unroll
    for (int mi = 0; mi < 2; ++mi) {
      int row = mi * 16 + lo;
      int c0  = (hi * 8) ^ ((row & 7) << 3);
      pa[mi] = *reinterpret_cast<const bf16x8*>(&Pl[wid][row * 64 + c0]);
    }
#pragma unroll
    for (int nf = 0; nf < 8; ++nf) {
      int row = nf * 16 + lo;
      bf16x8 vf = *reinterpret_cast<const bf16x8*>(
          &Vc[row * 32 + ((hi ^ (row & 3)) * 8)]);
#pragma unroll
      for (int mi = 0; mi < 2; ++mi)
        oa[mi][nf] = __builtin_amdgcn_mfma_f32_16x16x32_bf16(
            pa[mi], vf, oa[mi][nf], 0, 0, 0);
    }
    __syncthreads();   // staged tile ready; all waves done with buffer `cur`
    cur ^= 1;
  }
  // ---- epilogue: normalize, write (B,T,D) bf16 ----
  const int b = bh >> 4, h = bh & 15;
#pragma unroll
  for (int mi = 0; mi < 2; ++mi)
#pragma unroll
    for (int r = 0; r < 4; ++r) {
      float lr  = __shfl(lcol[mi], hi * 4 + r);   // denom for q-row hi*4+r
      float inv = 1.f / lr;
      int t = q0 + mi * 16 + hi * 4 + r;
#pragma unroll
      for (int nf = 0; nf < 8; ++nf)
        ob[(size_t)(b * Tz + t) * Dz + h * DHz + nf * 16 + lo] =
            f2bf(oa[mi][nf][r] * inv);
    }
}

// ---------------- launch ------------------------------------------------------
// Workspace budget note: qbuf/kbuf (2x33.5MB bf16) live INSIDE d_out (67.1MB
// fp32) — they are dead before the final O-projection GEMM fully overwrites
// d_out. d_ws use is only ~76.5MB.
extern "C" void kernel_launch(void* const* d_in, const int* in_sizes, int n_in,
                              void* d_out, int out_size, void* d_ws, size_t ws_size,
                              hipStream_t stream) {
  const float* x  = (const float*)d_in[0];
  const float* Wq = (const float*)d_in[1];
  const float* Wk = (const float*)d_in[2];
  const float* Wv = (const float*)d_in[3];
  const float* Wo = (const float*)d_in[4];

  char* ws = (char*)d_ws;
  unsigned short* xb    = (unsigned short*)(ws);              // 33.5MB, reused as attn out
  unsigned short* wslot = (unsigned short*)(ws + 33554432);   // 8.4MB (one converted W)
  unsigned short* vtb   = (unsigned short*)(ws + 41943040);   // 33.5MB (B,H,Dh,T)
  float* cosv = (float*)(ws + 75497472);                      // 512KB
  float* sinv = (float*)(ws + 76021760);                      // 512KB (end: 76.5MB)
  // q/k tensors inside d_out (67.1MB = exactly 2x 33.5MB)
  unsigned short* qbuf  = (unsigned short*)d_out;             // (B,H,T,Dh) bf16
  unsigned short* kbuf  = (unsigned short*)d_out + (size_t)Mz * Dz; // (B,H,T,Dh)

  rope_tab<<<512, 256, 0, stream>>>(cosv, sinv);
  cvt_bf16<<<16384, 256, 0, stream>>>(x, xb, Mz * Dz / 4);

  cvt_bf16<<<4096, 256, 0, stream>>>(Wq, wslot, Dz * Dz / 4);
  gemm_bt<1><<<1024, 256, 0, stream>>>(xb, wslot, qbuf);
  cvt_bf16<<<4096, 256, 0, stream>>>(Wk, wslot, Dz * Dz / 4);
  gemm_bt<1><<<1024, 256, 0, stream>>>(xb, wslot, kbuf);
  cvt_bf16<<<4096, 256, 0, stream>>>(Wv, wslot, Dz * Dz / 4);
  gemm_bt<2><<<1024, 256, 0, stream>>>(xb, wslot, vtb);

  // q gets log2(e)/sqrt(Dh) folded in (base-2 softmax); k unscaled
  rope_apply<<<4096, 256, 0, stream>>>(qbuf, cosv, sinv, 0.12751744900783237f);
  rope_apply<<<4096, 256, 0, stream>>>(kbuf, cosv, sinv, 1.0f);

  attn_fwd<<<1024, 256, 0, stream>>>(qbuf, kbuf, vtb, xb);

  cvt_bf16<<<4096, 256, 0, stream>>>(Wo, wslot, Dz * Dz / 4);
  gemm_bt<0><<<1024, 256, 0, stream>>>(xb, wslot, (float*)d_out);
}